// Round 11
// baseline (391.318 us; speedup 1.0000x reference)
//
#include <hip/hip_runtime.h>

// VectorQuantizer forward, MI355X. Split-bf16 MFMA GEMM (hi/lo, 3 products,
// K extended 256->768). Epilogue: argmin + per-block online-softmax partials
// (exact entropy) + racy-shrinking-threshold candidate capture. d^2-norm split
// in closed form (Gram + colsums + moments). R11: gram upper-triangle only
// (2*sum - diag fixup), gemm epilogue reuses acc as d-store, megaprep writes
// Es/Zs via 16B coalesced chunks. 3 kernels. T=4096 tokens, NE=16384 codes.

#define T_TOK 4096
#define NE    16384
#define KD    256
#define K3    768          // 3x split-extended K
#define CAP   768          // candidate slots per token (avg_probs only)
#define DCUT  0.15f        // capture window above best-so-far global min

#define NCB   512          // code prep blocks (32 rows each)
#define NZB   128          // z prep blocks (32 tokens each)
#define NGRAM 142          // gram strip jobs + 2 reduce blocks (placed first)
#define NGEMM 4096         // gemm blocks (32 x 128)

typedef __attribute__((ext_vector_type(8))) short bf16x8;
typedef __attribute__((ext_vector_type(4))) float f32x4;
typedef unsigned long long u64;

__device__ __forceinline__ short f2bf(float f) {
    unsigned u = __float_as_uint(f);
    u = (u + 0x7FFFu + ((u >> 16) & 1u)) >> 16;   // round-to-nearest-even
    return (short)u;
}
__device__ __forceinline__ float bf2f(short s) {
    return __uint_as_float(((unsigned)(unsigned short)s) << 16);
}
__device__ __forceinline__ unsigned pack2(short a, short b) {
    return (unsigned)(unsigned short)a | ((unsigned)(unsigned short)b << 16);
}
// codes-side split (scaled by -2, exact scaling)
__device__ __forceinline__ short conv_hi_e(float y) {
    return f2bf(-2.f * bf2f(f2bf(y)));
}
__device__ __forceinline__ short conv_lo_e(float y) {
    short l = f2bf(y - bf2f(f2bf(y)));
    return f2bf(-2.f * bf2f(l));
}
// z-side split (unscaled)
__device__ __forceinline__ short conv_hi_z(float y) { return f2bf(y); }
__device__ __forceinline__ short conv_lo_z(float y) {
    return f2bf(y - bf2f(f2bf(y)));
}

__device__ __forceinline__ void async_load16(const void* g, void* l) {
    __builtin_amdgcn_global_load_lds(
        (const __attribute__((address_space(1))) void*)g,
        (__attribute__((address_space(3))) void*)l, 16, 0, 0);
}

// ---------------- megaprep: codes | z | init, branch on blockIdx ----------------
__global__ __launch_bounds__(256)
void megaprep_kernel(const float* __restrict__ wk, const float* __restrict__ wg,
                     const float* __restrict__ z,
                     float* __restrict__ enorm, float* __restrict__ e2k,
                     float* __restrict__ e2s, short* __restrict__ Es,
                     float* __restrict__ znorm, float* __restrict__ z2k,
                     float* __restrict__ z2s, short* __restrict__ Zs,
                     float* __restrict__ SVeS, float* __restrict__ SVeV,
                     float* __restrict__ SVzS, float* __restrict__ SVzV,
                     float* __restrict__ mompart,
                     u64* __restrict__ packed, float* __restrict__ avg_num,
                     int* __restrict__ ncand, float* __restrict__ scal,
                     float* __restrict__ G, int* __restrict__ done_ctr) {
    int b = blockIdx.x, tid = threadIdx.x;
    if (b >= NCB + NZB) {                    // ---- init branch ----
        int gid = (b - NCB - NZB) * 256 + tid;
        for (int i = gid; i < 81920; i += 2048) G[i] = 0.f;
        for (int i = gid; i < NE; i += 2048) avg_num[i] = 0.f;
        for (int i = gid; i < T_TOK; i += 2048) { packed[i] = ~0ull; ncand[i] = 0; }
        if (gid < 8) scal[gid] = 0.f;
        if (gid == 8) *done_ctr = 0;
        return;
    }

    __shared__ float xs[32][257];            // 32.9 KB (odd pad: bank-friendly)
    __shared__ float ps[32][8];
    __shared__ float rnorm[32][2];
    __shared__ float rw[32][2];
    int c = tid;

    bool is_codes = (b < NCB);
    int n0;                                  // output row base
    if (is_codes) {                          // ---- codes load ----
        n0 = b * 32;
#pragma unroll
        for (int i = 0; i < 8; ++i) {
            int idx = tid + i * 256;
            xs[idx >> 6][idx & 63] = wk[(size_t)n0 * 64 + idx];
        }
#pragma unroll
        for (int i = 0; i < 24; ++i) {
            int idx = tid + i * 256;
            xs[idx / 192][64 + idx % 192] = wg[(size_t)n0 * 192 + idx];
        }
    } else {                                 // ---- z load (NCHW transpose) ----
        int jz = b - NCB;
        n0 = jz * 32;
        int bb = n0 >> 10, hw0 = n0 & 1023;
#pragma unroll
        for (int i = 0; i < 32; ++i) {
            int idx = tid + i * 256;
            int cc = idx >> 5, hwl = idx & 31;
            xs[hwl][cc] = z[(((size_t)bb * 256 + cc) << 10) + hw0 + hwl];
        }
    }
    __syncthreads();
    {
        int r = tid & 31, part = tid >> 5;
        float s = 0.f;
        for (int j = 0; j < 32; ++j) { float v = xs[r][part * 32 + j]; s = fmaf(v, v, s); }
        ps[r][part] = s;
    }
    __syncthreads();
    if (tid < 32) {
        float sk = ps[tid][0] + ps[tid][1];
        float sg = ps[tid][2] + ps[tid][3] + ps[tid][4] + ps[tid][5] + ps[tid][6] + ps[tid][7];
        float nk = fmaxf(sqrtf(sk), 1e-12f), ng = fmaxf(sqrtf(sg), 1e-12f);
        float v2k = sk / (nk * nk), v2g = sg / (ng * ng);
        rnorm[tid][0] = 1.f / nk; rnorm[tid][1] = 1.f / ng;
        rw[tid][0] = v2k; rw[tid][1] = v2g;
        if (is_codes) { e2k[n0 + tid] = v2k; e2s[n0 + tid] = v2k + v2g; }
        else          { z2k[n0 + tid] = v2k; z2s[n0 + tid] = v2k + v2g; }
    }
    __syncthreads();
    // fused normalize-in-place + column sums
    {
        int sel = (c < 64) ? 0 : 1;
        float S = 0.f, V = 0.f;
        for (int r = 0; r < 32; ++r) {
            float y = xs[r][c] * rnorm[r][sel];
            xs[r][c] = y;
            S += y; V = fmaf(rw[r][sel], y, V);
        }
        if (is_codes) { SVeS[(size_t)b * 256 + c] = S; SVeV[(size_t)b * 256 + c] = V; }
        else { int jz = b - NCB; SVzS[(size_t)jz * 256 + c] = S; SVzV[(size_t)jz * 256 + c] = V; }
    }
    __syncthreads();
    // fp32 norm write (float4, coalesced)
    {
        float* dst = is_codes ? enorm : znorm;
#pragma unroll
        for (int it = 0; it < 8; ++it) {
            int lin = tid + it * 256;
            int row = lin >> 6, c4 = (lin & 63) * 4;
            float4 v = {xs[row][c4], xs[row][c4 + 1], xs[row][c4 + 2], xs[row][c4 + 3]};
            *reinterpret_cast<float4*>(&dst[(size_t)(n0 + row) * KD + c4]) = v;
        }
    }
    // split-bf16 write: 16B chunks, segment decoded from offset
    {
        short* dst = is_codes ? Es : Zs;
#pragma unroll
        for (int it = 0; it < 12; ++it) {
            int lin = tid + it * 256;
            int row = lin / 96, o = (lin % 96) * 8;
            int cb; bool lo;
            if (is_codes) {                   // [sh_k|sl_k|sh_k|sh_g|sl_g|sh_g]
                if (o < 64)       { cb = o;            lo = false; }
                else if (o < 128) { cb = o - 64;       lo = true;  }
                else if (o < 192) { cb = o - 128;      lo = false; }
                else if (o < 384) { cb = 64 + o - 192; lo = false; }
                else if (o < 576) { cb = 64 + o - 384; lo = true;  }
                else              { cb = 64 + o - 576; lo = false; }
            } else {                          // [h_k|h_k|l_k|h_g|h_g|l_g]
                if (o < 64)       { cb = o;            lo = false; }
                else if (o < 128) { cb = o - 64;       lo = false; }
                else if (o < 192) { cb = o - 128;      lo = true;  }
                else if (o < 384) { cb = 64 + o - 192; lo = false; }
                else if (o < 576) { cb = 64 + o - 384; lo = false; }
                else              { cb = 64 + o - 576; lo = true;  }
            }
            unsigned wv[4];
#pragma unroll
            for (int p = 0; p < 4; ++p) {
                float y0 = xs[row][cb + 2 * p], y1 = xs[row][cb + 2 * p + 1];
                short s0, s1;
                if (is_codes) {
                    s0 = lo ? conv_lo_e(y0) : conv_hi_e(y0);
                    s1 = lo ? conv_lo_e(y1) : conv_hi_e(y1);
                } else {
                    s0 = lo ? conv_lo_z(y0) : conv_hi_z(y0);
                    s1 = lo ? conv_lo_z(y1) : conv_hi_z(y1);
                }
                wv[p] = pack2(s0, s1);
            }
            uint4 vv; vv.x = wv[0]; vv.y = wv[1]; vv.z = wv[2]; vv.w = wv[3];
            *reinterpret_cast<uint4*>(dst + (size_t)(n0 + row) * K3 + o) = vv;
        }
    }
    // moments partials
    if (tid < 32) {
        float a = rw[tid][0], g = rw[tid][1];
        float s0 = a, s1 = a * a, s2 = g, s3 = g * g;
#pragma unroll
        for (int m = 1; m < 32; m <<= 1) {
            s0 += __shfl_xor(s0, m, 64); s1 += __shfl_xor(s1, m, 64);
            s2 += __shfl_xor(s2, m, 64); s3 += __shfl_xor(s3, m, 64);
        }
        if (tid == 0) {
            mompart[b * 4 + 0] = s0; mompart[b * 4 + 1] = s1;
            mompart[b * 4 + 2] = s2; mompart[b * 4 + 3] = s3;
        }
    }
}

// ---------------- gram strip: 32-col i-strip x cols [i0s,W), upper-tri store -------
template <int JW>
__device__ __forceinline__ void gram_strip(const float* __restrict__ X, float* __restrict__ G,
                                           int W, int i0s, int r0, int rows, int c0,
                                           float* xs, int tid) {
    int ia = tid >> 5, jb = tid & 31;
    int jbase = i0s + jb * JW;
    float acc[4][JW];
#pragma unroll
    for (int a = 0; a < 4; ++a)
#pragma unroll
        for (int u = 0; u < JW; ++u) acc[a][u] = 0.f;
    for (int rb = 0; rb < rows; rb += 16) {
        __syncthreads();
        int nf4 = 4 * W;
        for (int lin = tid; lin < nf4; lin += 256) {
            int r = lin / (W >> 2), f4 = lin % (W >> 2);
            *(float4*)&xs[r * W + f4 * 4] =
                *(const float4*)&X[(size_t)(r0 + rb + r) * KD + c0 + f4 * 4];
        }
        __syncthreads();
#pragma unroll 4
        for (int r = 0; r < 16; ++r) {
            float4 xi = *(const float4*)&xs[r * W + i0s + ia * 4];
            float xj[JW];
#pragma unroll
            for (int u = 0; u < JW; ++u) xj[u] = xs[r * W + jbase + u];
#pragma unroll
            for (int a = 0; a < 4; ++a)
#pragma unroll
                for (int u = 0; u < JW; ++u)
                    acc[a][u] = fmaf(xi[a], xj[u], acc[a][u]);
        }
    }
#pragma unroll
    for (int a = 0; a < 4; ++a) {
        int i = i0s + ia * 4 + a;
#pragma unroll
        for (int u = 0; u < JW; ++u) {
            int j = jbase + u;
            if (j >= i) atomicAdd(&G[i * W + j], acc[a][u]);
        }
    }
}

// ---------------- fused Gram (HEAD) + GEMM ----------------
__global__ __launch_bounds__(256, 4)
void gemm_gram_kernel(const short* __restrict__ Zs, const short* __restrict__ Es,
                      const float* __restrict__ z2s, const float* __restrict__ e2s,
                      u64* __restrict__ packed, float* __restrict__ scal,
                      float* __restrict__ part_m, float* __restrict__ part_z,
                      float* __restrict__ part_w,
                      float* __restrict__ candD, int* __restrict__ candN,
                      int* __restrict__ ncand,
                      const float* __restrict__ znorm, const float* __restrict__ enorm,
                      float* __restrict__ Gbuf,
                      const float* __restrict__ SVeS, const float* __restrict__ SVeV,
                      const float* __restrict__ SVzS, const float* __restrict__ SVzV,
                      const float* __restrict__ mompart,
                      float* __restrict__ SV, float* __restrict__ mom) {
    __shared__ __align__(16) char smem[32768];
    const int gid = blockIdx.x, tid = threadIdx.x;

    if (gid < NGRAM) {                        // =============== GRAM path ===============
        int b = gid;
        float* xs = (float*)smem;
        float* r1 = (float*)(smem + 12288);
        float* r2 = (float*)(smem + 13312);

        if (b == 140) {                       // SV reduce
            int c = tid;
            float s = 0.f, v = 0.f;
            for (int j = 0; j < NZB; ++j) { s += SVzS[(size_t)j * 256 + c]; v += SVzV[(size_t)j * 256 + c]; }
            SV[c] = s; SV[256 + c] = v;
            s = 0.f; v = 0.f;
            for (int j = 0; j < NCB; ++j) { s += SVeS[(size_t)j * 256 + c]; v += SVeV[(size_t)j * 256 + c]; }
            SV[512 + c] = s; SV[768 + c] = v;
            return;
        }
        if (b == 141) {                       // moments reduce
            int q = tid & 3, grp = tid >> 2;
            float accE = 0.f, accZ = 0.f;
            for (int j = grp; j < NCB; j += 64) accE += mompart[j * 4 + q];
            for (int j = NCB + grp; j < NCB + NZB; j += 64) accZ += mompart[j * 4 + q];
            r1[tid] = accE; r2[tid] = accZ;
            __syncthreads();
            for (int st = 32; st > 0; st >>= 1) {
                if (grp < st) { r1[tid] += r1[tid + st * 4]; r2[tid] += r2[tid + st * 4]; }
                __syncthreads();
            }
            if (grp == 0) { mom[4 + q] = r1[q]; mom[q] = r2[q]; }
            return;
        }
        // strips: [0,96) E-g | [96,112) E-k | [112,136) Z-g | [136,140) Z-k
        if (b < 96) {
            int s = b >> 4, ks = b & 15;
            const float* X = enorm; float* G = Gbuf + 4096;
            switch (s) {
                case 0: gram_strip<6>(X, G, 192, 0,   ks * 1024, 1024, 64, xs, tid); break;
                case 1: gram_strip<5>(X, G, 192, 32,  ks * 1024, 1024, 64, xs, tid); break;
                case 2: gram_strip<4>(X, G, 192, 64,  ks * 1024, 1024, 64, xs, tid); break;
                case 3: gram_strip<3>(X, G, 192, 96,  ks * 1024, 1024, 64, xs, tid); break;
                case 4: gram_strip<2>(X, G, 192, 128, ks * 1024, 1024, 64, xs, tid); break;
                default: gram_strip<1>(X, G, 192, 160, ks * 1024, 1024, 64, xs, tid); break;
            }
        } else if (b < 112) {
            int l = b - 96, s = l >> 3, ks = l & 7;
            if (s == 0) gram_strip<2>(enorm, Gbuf, 64, 0,  ks * 2048, 2048, 0, xs, tid);
            else        gram_strip<1>(enorm, Gbuf, 64, 32, ks * 2048, 2048, 0, xs, tid);
        } else if (b < 136) {
            int l = b - 112, s = l >> 2, ks = l & 3;
            const float* X = znorm; float* G = Gbuf + 45056;
            switch (s) {
                case 0: gram_strip<6>(X, G, 192, 0,   ks * 1024, 1024, 64, xs, tid); break;
                case 1: gram_strip<5>(X, G, 192, 32,  ks * 1024, 1024, 64, xs, tid); break;
                case 2: gram_strip<4>(X, G, 192, 64,  ks * 1024, 1024, 64, xs, tid); break;
                case 3: gram_strip<3>(X, G, 192, 96,  ks * 1024, 1024, 64, xs, tid); break;
                case 4: gram_strip<2>(X, G, 192, 128, ks * 1024, 1024, 64, xs, tid); break;
                default: gram_strip<1>(X, G, 192, 160, ks * 1024, 1024, 64, xs, tid); break;
            }
        } else {
            int l = b - 136, s = l >> 1, ks = l & 1;
            if (s == 0) gram_strip<2>(znorm, Gbuf + 40960, 64, 0,  ks * 2048, 2048, 0, xs, tid);
            else        gram_strip<1>(znorm, Gbuf + 40960, 64, 32, ks * 2048, 2048, 0, xs, tid);
        }
        return;
    }

    // =============== GEMM path ===============
    short* As = (short*)smem;                 // [128][64]
    short* Bs = As + 128 * 64;
    const int g = gid - NGRAM;
    const int lane = tid & 63, wid = tid >> 6;
    const int wm = wid >> 1, wn = wid & 1;
    const int t0 = (g & 31) * 128, n0 = (g >> 5) * 128;

    f32x4 acc[4][4];
#pragma unroll
    for (int bi = 0; bi < 4; ++bi)
#pragma unroll
        for (int bj = 0; bj < 4; ++bj) {
            f32x4 zz = {0.f, 0.f, 0.f, 0.f};
            acc[bi][bj] = zz;
        }

    auto stage = [&](int k0) {
        const int rb0 = wid * 32;
#pragma unroll
        for (int c2 = 0; c2 < 4; ++c2) {
            int rb = rb0 + c2 * 8;
            int row = rb + (lane >> 3);
            int q = (lane & 7) ^ (lane >> 3);   // XOR-quad swizzle (rb%8==0)
            async_load16(Zs + (size_t)(t0 + row) * K3 + k0 + q * 8, &As[rb * 64]);
            async_load16(Es + (size_t)(n0 + row) * K3 + k0 + q * 8, &Bs[rb * 64]);
        }
    };
    auto compute_half = [&](int s) {
        bf16x8 bfv[4];
#pragma unroll
        for (int bj = 0; bj < 4; ++bj) {
            int brow = wn * 64 + bj * 16 + (lane & 15);
            int q = ((s << 2) | (lane >> 4)) ^ (brow & 7);
            bfv[bj] = *reinterpret_cast<const bf16x8*>(&Bs[brow * 64 + q * 8]);
        }
#pragma unroll
        for (int bi = 0; bi < 4; ++bi) {
            int arow = wm * 64 + bi * 16 + (lane & 15);
            int q = ((s << 2) | (lane >> 4)) ^ (arow & 7);
            bf16x8 af = *reinterpret_cast<const bf16x8*>(&As[arow * 64 + q * 8]);
#pragma unroll
            for (int bj = 0; bj < 4; ++bj)
                acc[bi][bj] = __builtin_amdgcn_mfma_f32_16x16x32_bf16(
                    af, bfv[bj], acc[bi][bj], 0, 0, 0);
        }
    };

    int k0 = 0;
    for (int r = 0; r < 12; ++r) {
        stage(k0); __syncthreads();
        compute_half(0); compute_half(1);
        __syncthreads(); k0 += 64;
    }

    // ---- epilogue ----
    u64*   tokmin = (u64*)smem;               // [128][2]
    float* bmf    = (float*)(smem + 2048);    // [128]
    float* bthr   = (float*)(smem + 2560);    // [128]
    float* pzw    = (float*)(smem + 3072);    // [128][2][2]

    float e2sv[4];
#pragma unroll
    for (int bj = 0; bj < 4; ++bj)
        e2sv[bj] = e2s[n0 + wn * 64 + bj * 16 + (lane & 15)];

    // pass 1: d = z2s+e2s+acc (stored back into acc) + packed min
#pragma unroll
    for (int bi = 0; bi < 4; ++bi) {
        u64 pmin[4] = {~0ull, ~0ull, ~0ull, ~0ull};
        f32x4 z4 = *reinterpret_cast<const f32x4*>(
            &z2s[t0 + wm * 64 + bi * 16 + (lane >> 4) * 4]);
#pragma unroll
        for (int reg = 0; reg < 4; ++reg) {
#pragma unroll
            for (int bj = 0; bj < 4; ++bj) {
                float d = z4[reg] + e2sv[bj] + acc[bi][bj][reg];
                acc[bi][bj][reg] = d;          // reuse acc as d-store
                int n = n0 + wn * 64 + bj * 16 + (lane & 15);
                u64 pv = (((u64)__float_as_uint(d)) << 32) | (unsigned)n;
                if (pv < pmin[reg]) pmin[reg] = pv;
            }
        }
#pragma unroll
        for (int m = 1; m < 16; m <<= 1)
#pragma unroll
            for (int reg = 0; reg < 4; ++reg) {
                u64 o = __shfl_xor(pmin[reg], m, 64);
                if (o < pmin[reg]) pmin[reg] = o;
            }
        if ((lane & 15) == 0) {
#pragma unroll
            for (int reg = 0; reg < 4; ++reg) {
                int tl = wm * 64 + bi * 16 + (lane >> 4) * 4 + reg;
                tokmin[tl * 2 + wn] = pmin[reg];
            }
        }
    }
    __syncthreads();

    if (tid < 128) {
        int tl = tid;
        u64 bm = tokmin[tl * 2], b1 = tokmin[tl * 2 + 1];
        if (b1 < bm) bm = b1;
        u64 old = atomicMin(&packed[t0 + tl], bm);
        u64 gb = (old < bm) ? old : bm;
        float d_bmin = __uint_as_float((unsigned)(bm >> 32));
        bmf[tl] = -100.f * d_bmin;
        bthr[tl] = __uint_as_float((unsigned)(gb >> 32)) + DCUT;
    }
    __syncthreads();

    // pass 2: softmax partials + capture, d read from acc
#pragma unroll
    for (int bi = 0; bi < 4; ++bi) {
        float ez[4] = {0.f, 0.f, 0.f, 0.f}, ew[4] = {0.f, 0.f, 0.f, 0.f};
#pragma unroll
        for (int reg = 0; reg < 4; ++reg) {
            int tl = wm * 64 + bi * 16 + (lane >> 4) * 4 + reg;
            int t = t0 + tl;
            float m_b = bmf[tl], thr = bthr[tl];
#pragma unroll
            for (int bj = 0; bj < 4; ++bj) {
                float d = acc[bi][bj][reg];
                float a = -100.f * d;
                float e = __expf(a - m_b);
                ez[reg] += e;
                ew[reg] = fmaf(a, e, ew[reg]);
                if (d <= thr) {
                    int pos = atomicAdd(&ncand[t], 1);
                    if (pos < CAP) {
                        candD[(size_t)t * CAP + pos] = d;
                        candN[(size_t)t * CAP + pos] = n0 + wn * 64 + bj * 16 + (lane & 15);
                    }
                }
            }
        }
#pragma unroll
        for (int m = 1; m < 16; m <<= 1)
#pragma unroll
            for (int reg = 0; reg < 4; ++reg) {
                ez[reg] += __shfl_xor(ez[reg], m, 64);
                ew[reg] += __shfl_xor(ew[reg], m, 64);
            }
        if ((lane & 15) == 0) {
#pragma unroll
            for (int reg = 0; reg < 4; ++reg) {
                int tl = wm * 64 + bi * 16 + (lane >> 4) * 4 + reg;
                pzw[(tl * 2 + wn) * 2 + 0] = ez[reg];
                pzw[(tl * 2 + wn) * 2 + 1] = ew[reg];
            }
        }
    }
    __syncthreads();

    if (tid < 128) {
        int tl = tid;
        size_t o = (size_t)(g >> 5) * T_TOK + t0 + tl;
        part_m[o] = bmf[tl];
        part_z[o] = pzw[tl * 4 + 0] + pzw[tl * 4 + 2];
        part_w[o] = pzw[tl * 4 + 1] + pzw[tl * 4 + 3];
    }
}

// ---------------- combine + zq + scatter + last-block finalize ----------------
__global__ __launch_bounds__(256)
void combine_final_kernel(const float* __restrict__ part_m, const float* __restrict__ part_z,
                          const float* __restrict__ part_w, const u64* __restrict__ packed,
                          const float* __restrict__ enorm, const float* __restrict__ znorm,
                          const float* __restrict__ candD, const int* __restrict__ candN,
                          const int* __restrict__ ncand, float* __restrict__ avg_num,
                          float* __restrict__ scal, int* __restrict__ done_ctr,
                          const float* __restrict__ G, const float* __restrict__ SV,
                          const float* __restrict__ mom, float* __restrict__ out) {
    __shared__ float sm[32][8], sz[32][8], sw[32][8];
    __shared__ float Ms[32], Zts[32];
    __shared__ int idxs[32];
    __shared__ float q_lds[256][33];
    __shared__ float red[256];
    __shared__ int lastf;
    int tid = threadIdx.x, tl = tid & 31, q = tid >> 5;
    int tbase = blockIdx.x * 32;
    int t = tbase + tl;

    // phase 1: online-softmax combine (8-way split over 128 n-blocks)
    float m = -3.0e38f, Z = 0.f, W = 0.f;
    for (int nb = q * 16; nb < q * 16 + 16; ++nb) {
        size_t o = (size_t)nb * T_TOK + t;
        float mb = part_m[o], zb = part_z[o], wb = part_w[o];
        if (mb > m) { float s = __expf(m - mb); Z *= s; W *= s; m = mb; }
        float s2 = __expf(mb - m);
        Z = fmaf(zb, s2, Z); W = fmaf(wb, s2, W);
    }
    sm[tl][q] = m; sz[tl][q] = Z; sw[tl][q] = W;
    __syncthreads();
    if (tid < 32) {
        float M = sm[tid][0], Zt = sz[tid][0], Wt = sw[tid][0];
#pragma unroll
        for (int qq = 1; qq < 8; ++qq) {
            float mb = sm[tid][qq], Zb = sz[tid][qq], Wb = sw[tid][qq];
            if (mb > M) { float s = __expf(M - mb); Zt *= s; Wt *= s; M = mb; }
            float s2 = __expf(mb - M);
            Zt = fmaf(Zb, s2, Zt); Wt = fmaf(Wb, s2, Wt);
        }
        int tt = tbase + tid;
        Ms[tid] = M; Zts[tid] = Zt;
        u64 pv = packed[tt];
        int idx = (int)(pv & 0xFFFFFFFFull);
        idxs[tid] = idx;
        out[1048581 + tt] = (float)idx;
        float ent = M + logf(Zt) - Wt / Zt;
#pragma unroll
        for (int mm = 1; mm < 32; mm <<= 1) ent += __shfl_xor(ent, mm, 64);
        if (tid == 0) atomicAdd(&scal[3], ent);
    }
    __syncthreads();

    // phase 2: z_q gather + transpose + vq loss (32 tokens)
    float sdq = 0.f;
    for (int tl2 = 0; tl2 < 32; ++tl2) {
        int tt = tbase + tl2;
        float qv = enorm[(size_t)idxs[tl2] * KD + tid];
        q_lds[tid][tl2] = qv;
        float zc = znorm[(size_t)tt * KD + tid];
        float df = qv - zc;
        sdq = fmaf(df, df, sdq);
    }
    __syncthreads();
    {
        int bb = tbase >> 10, hw0 = tbase & 1023;
        int cg = tid >> 5, hwl = tid & 31;
        for (int c0 = 0; c0 < 256; c0 += 8) {
            int c = c0 + cg;
            out[(((size_t)(bb * 256 + c)) << 10) + hw0 + hwl] = q_lds[c][hwl];
        }
    }
    red[tid] = sdq;
    __syncthreads();
    for (int s = 128; s > 0; s >>= 1) { if (tid < s) red[tid] += red[tid + s]; __syncthreads(); }
    if (tid == 0) atomicAdd(&scal[2], red[0]);

    // phase 3: avg_probs scatter (8 lanes per token)
    {
        int tok = tid >> 3, sub = tid & 7;
        int tt = tbase + tok;
        int nc = min(ncand[tt], CAP);
        float M = Ms[tok], Zt = Zts[tok];
        for (int i = sub; i < nc; i += 8) {
            float a = -100.f * candD[(size_t)tt * CAP + i];
            atomicAdd(&avg_num[candN[(size_t)tt * CAP + i]], __expf(a - M) / Zt);
        }
    }

    // phase 4: last block does finalize
    __syncthreads();
    __threadfence();
    if (tid == 0) lastf = (atomicAdd(done_ctr, 1) == 127) ? 1 : 0;
    __syncthreads();
    if (!lastf) return;
    __threadfence();

    float s = 0.f;
    for (int n = tid; n < NE; n += 256) {
        float avg = atomicAdd(&avg_num[n], 0.f) * (1.f / 4096.f);
        s += avg * logf(avg + 1e-5f);
    }
    red[tid] = s; __syncthreads();
    for (int st = 128; st > 0; st >>= 1) { if (tid < st) red[tid] += red[tid + st]; __syncthreads(); }
    float avg_ent_neg = red[0];
    __syncthreads();

    // G is upper-triangle only: <Gz,Ge>_full = 2*sum_upper - sum_diag
    const float* G_ek = G;
    const float* G_eg = G + 4096;
    const float* G_zk = G + 40960;
    const float* G_zg = G + 45056;
    float rk = 0.f, rg = 0.f;
    for (int i = tid; i < 4096; i += 256)  rk = fmaf(G_zk[i], G_ek[i], rk);
    for (int i = tid; i < 36864; i += 256) rg = fmaf(G_zg[i], G_eg[i], rg);
    rk *= 2.f; rg *= 2.f;
    for (int i = tid; i < 64; i += 256)  rk -= G_zk[i * 65]  * G_ek[i * 65];
    for (int i = tid; i < 192; i += 256) rg -= G_zg[i * 193] * G_eg[i * 193];
    {
        int c = tid;
        float v = SV[256 + c] * SV[512 + c] + SV[c] * SV[768 + c];
        if (c < 64) rk -= v; else rg -= v;
    }
    red[tid] = 4.f * rk; __syncthreads();
    for (int st = 128; st > 0; st >>= 1) { if (tid < st) red[tid] += red[tid + st]; __syncthreads(); }
    float red_k = red[0];
    __syncthreads();
    red[tid] = 4.f * rg; __syncthreads();
    for (int st = 128; st > 0; st >>= 1) { if (tid < st) red[tid] += red[tid + st]; __syncthreads(); }
    float red_g = red[0];

    if (tid == 0) {
        float term1k = NE * mom[1] + 2.f * mom[0] * mom[4] + T_TOK * mom[5];
        float term1g = NE * mom[3] + 2.f * mom[2] * mom[6] + T_TOK * mom[7];
        float sdk2 = term1k + red_k;
        float sdg2 = term1g + red_g;
        float avg_ent = -avg_ent_neg;
        float se = atomicAdd(&scal[3], 0.f) * (1.f / 4096.f);
        float vq = atomicAdd(&scal[2], 0.f) * (1.f / 1048576.f);
        out[1048576] = vq;
        out[1048577] = 0.25f * vq;
        out[1048578] = 0.1f * (se - avg_ent);
        out[1048579] = sdk2 * (1.f / 4096.f);
        out[1048580] = sdg2 * (1.f / 4096.f);
    }
}

// ---------------- host ----------------
extern "C" void kernel_launch(void* const* d_in, const int* in_sizes, int n_in,
                              void* d_out, int out_size, void* d_ws, size_t ws_size,
                              hipStream_t stream) {
    const float* z  = (const float*)d_in[0];
    const float* wk = (const float*)d_in[1];
    const float* wg = (const float*)d_in[2];
    float* out = (float*)d_out;

    char* ws = (char*)d_ws;
    size_t off = 0;
    auto alloc = [&](size_t bytes) {
        void* p = ws + off;
        off += (bytes + 255) & ~(size_t)255;
        return p;
    };
    float* enorm  = (float*)alloc((size_t)NE * KD * 4);
    float* znorm  = (float*)alloc((size_t)T_TOK * KD * 4);
    short* Es     = (short*)alloc((size_t)NE * K3 * 2);
    short* Zs     = (short*)alloc((size_t)T_TOK * K3 * 2);
    float* e2k    = (float*)alloc(NE * 4);
    float* e2s    = (float*)alloc(NE * 4);
    float* z2k    = (float*)alloc(T_TOK * 4);
    float* z2s    = (float*)alloc(T_TOK * 4);
    u64*   packed = (u64*)alloc(T_TOK * 8);
    int*   ncand  = (int*)alloc(T_TOK * 4);
    float* part_m = (float*)alloc((size_t)(NE / 128) * T_TOK * 4);
    float* part_z = (float*)alloc((size_t)(NE / 128) * T_TOK * 4);
    float* part_w = (float*)alloc((size_t)(NE / 128) * T_TOK * 4);
    float* candD  = (float*)alloc((size_t)T_TOK * CAP * 4);
    int*   candN  = (int*)alloc((size_t)T_TOK * CAP * 4);
    float* avg_num= (float*)alloc(NE * 4);
    float* scal   = (float*)alloc(8 * 4);
    float* Gbuf   = (float*)alloc(81920 * 4);
    float* SV     = (float*)alloc(1024 * 4);
    float* momv   = (float*)alloc(8 * 4);
    float* SVeS   = (float*)alloc((size_t)NCB * 256 * 4);
    float* SVeV   = (float*)alloc((size_t)NCB * 256 * 4);
    float* SVzS   = (float*)alloc((size_t)NZB * 256 * 4);
    float* SVzV   = (float*)alloc((size_t)NZB * 256 * 4);
    float* mompart= (float*)alloc((size_t)(NCB + NZB) * 4 * 4);
    int*   done_ctr = (int*)alloc(256);

    megaprep_kernel<<<NCB + NZB + 8, 256, 0, stream>>>(
        wk, wg, z, enorm, e2k, e2s, Es, znorm, z2k, z2s, Zs,
        SVeS, SVeV, SVzS, SVzV, mompart, packed, avg_num, ncand, scal, Gbuf, done_ctr);

    gemm_gram_kernel<<<NGRAM + NGEMM, 256, 0, stream>>>(
        Zs, Es, z2s, e2s, packed, scal, part_m, part_z, part_w,
        candD, candN, ncand, znorm, enorm, Gbuf,
        SVeS, SVeV, SVzS, SVzV, mompart, SV, momv);

    combine_final_kernel<<<T_TOK / 32, 256, 0, stream>>>(
        part_m, part_z, part_w, packed, enorm, znorm,
        candD, candN, ncand, avg_num, scal, done_ctr, Gbuf, SV, momv, out);
}

// Round 12
// 373.138 us; speedup vs baseline: 1.0487x; 1.0487x over previous
//
#include <hip/hip_runtime.h>

// VectorQuantizer forward, MI355X. Split-bf16 MFMA GEMM (hi/lo, 3 products,
// K extended 256->768). Epilogue: argmin + per-block online-softmax partials
// (exact entropy) + racy-shrinking-threshold candidate capture. d^2-norm split
// in closed form (Gram + colsums + moments). R12: gram/gemm reverted to R10
// exactly (R11's runtime-W gram spilled ~70MB to scratch); megaprep keeps
// R11's coalesced 16B Es/Zs chunk writes. 3 kernels. T=4096, NE=16384.

#define T_TOK 4096
#define NE    16384
#define KD    256
#define K3    768          // 3x split-extended K
#define CAP   768          // candidate slots per token (avg_probs only)
#define DCUT  0.15f        // capture window above best-so-far global min

#define NCB   512          // code prep blocks (32 rows each)
#define NZB   128          // z prep blocks (32 tokens each)
#define NGRAM 142          // gram strip jobs + 2 reduce blocks (placed first)
#define NGEMM 4096         // gemm blocks (32 x 128)

typedef __attribute__((ext_vector_type(8))) short bf16x8;
typedef __attribute__((ext_vector_type(4))) float f32x4;
typedef unsigned long long u64;

__device__ __forceinline__ short f2bf(float f) {
    unsigned u = __float_as_uint(f);
    u = (u + 0x7FFFu + ((u >> 16) & 1u)) >> 16;   // round-to-nearest-even
    return (short)u;
}
__device__ __forceinline__ float bf2f(short s) {
    return __uint_as_float(((unsigned)(unsigned short)s) << 16);
}
__device__ __forceinline__ unsigned pack2(short a, short b) {
    return (unsigned)(unsigned short)a | ((unsigned)(unsigned short)b << 16);
}
// codes-side split (scaled by -2, exact scaling)
__device__ __forceinline__ short conv_hi_e(float y) {
    return f2bf(-2.f * bf2f(f2bf(y)));
}
__device__ __forceinline__ short conv_lo_e(float y) {
    short l = f2bf(y - bf2f(f2bf(y)));
    return f2bf(-2.f * bf2f(l));
}
// z-side split (unscaled)
__device__ __forceinline__ short conv_hi_z(float y) { return f2bf(y); }
__device__ __forceinline__ short conv_lo_z(float y) {
    return f2bf(y - bf2f(f2bf(y)));
}

__device__ __forceinline__ void async_load16(const void* g, void* l) {
    __builtin_amdgcn_global_load_lds(
        (const __attribute__((address_space(1))) void*)g,
        (__attribute__((address_space(3))) void*)l, 16, 0, 0);
}

// ---------------- megaprep: codes | z | init, branch on blockIdx ----------------
__global__ __launch_bounds__(256)
void megaprep_kernel(const float* __restrict__ wk, const float* __restrict__ wg,
                     const float* __restrict__ z,
                     float* __restrict__ enorm, float* __restrict__ e2k,
                     float* __restrict__ e2s, short* __restrict__ Es,
                     float* __restrict__ znorm, float* __restrict__ z2k,
                     float* __restrict__ z2s, short* __restrict__ Zs,
                     float* __restrict__ SVeS, float* __restrict__ SVeV,
                     float* __restrict__ SVzS, float* __restrict__ SVzV,
                     float* __restrict__ mompart,
                     u64* __restrict__ packed, float* __restrict__ avg_num,
                     int* __restrict__ ncand, float* __restrict__ scal,
                     float* __restrict__ G, int* __restrict__ done_ctr) {
    int b = blockIdx.x, tid = threadIdx.x;
    if (b >= NCB + NZB) {                    // ---- init branch ----
        int gid = (b - NCB - NZB) * 256 + tid;
        for (int i = gid; i < 81920; i += 2048) G[i] = 0.f;
        for (int i = gid; i < NE; i += 2048) avg_num[i] = 0.f;
        for (int i = gid; i < T_TOK; i += 2048) { packed[i] = ~0ull; ncand[i] = 0; }
        if (gid < 8) scal[gid] = 0.f;
        if (gid == 8) *done_ctr = 0;
        return;
    }

    __shared__ float xs[32][257];            // 32.9 KB
    __shared__ float ps[32][8];
    __shared__ float rnorm[32][2];
    __shared__ float rw[32][2];
    int c = tid;

    bool is_codes = (b < NCB);
    int n0;
    if (is_codes) {                          // ---- codes load ----
        n0 = b * 32;
#pragma unroll
        for (int i = 0; i < 8; ++i) {
            int idx = tid + i * 256;
            xs[idx >> 6][idx & 63] = wk[(size_t)n0 * 64 + idx];
        }
#pragma unroll
        for (int i = 0; i < 24; ++i) {
            int idx = tid + i * 256;
            xs[idx / 192][64 + idx % 192] = wg[(size_t)n0 * 192 + idx];
        }
    } else {                                 // ---- z load (NCHW transpose) ----
        int jz = b - NCB;
        n0 = jz * 32;
        int bb = n0 >> 10, hw0 = n0 & 1023;
#pragma unroll
        for (int i = 0; i < 32; ++i) {
            int idx = tid + i * 256;
            int cc = idx >> 5, hwl = idx & 31;
            xs[hwl][cc] = z[(((size_t)bb * 256 + cc) << 10) + hw0 + hwl];
        }
    }
    __syncthreads();
    {
        int r = tid & 31, part = tid >> 5;
        float s = 0.f;
        for (int j = 0; j < 32; ++j) { float v = xs[r][part * 32 + j]; s = fmaf(v, v, s); }
        ps[r][part] = s;
    }
    __syncthreads();
    if (tid < 32) {
        float sk = ps[tid][0] + ps[tid][1];
        float sg = ps[tid][2] + ps[tid][3] + ps[tid][4] + ps[tid][5] + ps[tid][6] + ps[tid][7];
        float nk = fmaxf(sqrtf(sk), 1e-12f), ng = fmaxf(sqrtf(sg), 1e-12f);
        float v2k = sk / (nk * nk), v2g = sg / (ng * ng);
        rnorm[tid][0] = 1.f / nk; rnorm[tid][1] = 1.f / ng;
        rw[tid][0] = v2k; rw[tid][1] = v2g;
        if (is_codes) { e2k[n0 + tid] = v2k; e2s[n0 + tid] = v2k + v2g; }
        else          { z2k[n0 + tid] = v2k; z2s[n0 + tid] = v2k + v2g; }
    }
    __syncthreads();
    // fused normalize-in-place + column sums
    {
        int sel = (c < 64) ? 0 : 1;
        float S = 0.f, V = 0.f;
        for (int r = 0; r < 32; ++r) {
            float y = xs[r][c] * rnorm[r][sel];
            xs[r][c] = y;
            S += y; V = fmaf(rw[r][sel], y, V);
        }
        if (is_codes) { SVeS[(size_t)b * 256 + c] = S; SVeV[(size_t)b * 256 + c] = V; }
        else { int jz = b - NCB; SVzS[(size_t)jz * 256 + c] = S; SVzV[(size_t)jz * 256 + c] = V; }
    }
    __syncthreads();
    // fp32 norm write (float4, coalesced)
    {
        float* dst = is_codes ? enorm : znorm;
#pragma unroll
        for (int it = 0; it < 8; ++it) {
            int lin = tid + it * 256;
            int row = lin >> 6, c4 = (lin & 63) * 4;
            float4 v = {xs[row][c4], xs[row][c4 + 1], xs[row][c4 + 2], xs[row][c4 + 3]};
            *reinterpret_cast<float4*>(&dst[(size_t)(n0 + row) * KD + c4]) = v;
        }
    }
    // split-bf16 write: 16B chunks, segment decoded from offset
    {
        short* dst = is_codes ? Es : Zs;
#pragma unroll
        for (int it = 0; it < 12; ++it) {
            int lin = tid + it * 256;
            int row = lin / 96, o = (lin % 96) * 8;
            int cb; bool lo;
            if (is_codes) {                   // [sh_k|sl_k|sh_k|sh_g|sl_g|sh_g]
                if (o < 64)       { cb = o;            lo = false; }
                else if (o < 128) { cb = o - 64;       lo = true;  }
                else if (o < 192) { cb = o - 128;      lo = false; }
                else if (o < 384) { cb = 64 + o - 192; lo = false; }
                else if (o < 576) { cb = 64 + o - 384; lo = true;  }
                else              { cb = 64 + o - 576; lo = false; }
            } else {                          // [h_k|h_k|l_k|h_g|h_g|l_g]
                if (o < 64)       { cb = o;            lo = false; }
                else if (o < 128) { cb = o - 64;       lo = false; }
                else if (o < 192) { cb = o - 128;      lo = true;  }
                else if (o < 384) { cb = 64 + o - 192; lo = false; }
                else if (o < 576) { cb = 64 + o - 384; lo = false; }
                else              { cb = 64 + o - 576; lo = true;  }
            }
            unsigned wv[4];
#pragma unroll
            for (int p = 0; p < 4; ++p) {
                float y0 = xs[row][cb + 2 * p], y1 = xs[row][cb + 2 * p + 1];
                short s0, s1;
                if (is_codes) {
                    s0 = lo ? conv_lo_e(y0) : conv_hi_e(y0);
                    s1 = lo ? conv_lo_e(y1) : conv_hi_e(y1);
                } else {
                    s0 = lo ? conv_lo_z(y0) : conv_hi_z(y0);
                    s1 = lo ? conv_lo_z(y1) : conv_hi_z(y1);
                }
                wv[p] = pack2(s0, s1);
            }
            uint4 vv; vv.x = wv[0]; vv.y = wv[1]; vv.z = wv[2]; vv.w = wv[3];
            *reinterpret_cast<uint4*>(dst + (size_t)(n0 + row) * K3 + o) = vv;
        }
    }
    // moments partials
    if (tid < 32) {
        float a = rw[tid][0], g = rw[tid][1];
        float s0 = a, s1 = a * a, s2 = g, s3 = g * g;
#pragma unroll
        for (int m = 1; m < 32; m <<= 1) {
            s0 += __shfl_xor(s0, m, 64); s1 += __shfl_xor(s1, m, 64);
            s2 += __shfl_xor(s2, m, 64); s3 += __shfl_xor(s3, m, 64);
        }
        if (tid == 0) {
            mompart[b * 4 + 0] = s0; mompart[b * 4 + 1] = s1;
            mompart[b * 4 + 2] = s2; mompart[b * 4 + 3] = s3;
        }
    }
}

// ---------------- gram strip job: 32-col i-strip x full W, register acc (R10) --------
template <int W>
__device__ __forceinline__ void gram_strip(const float* __restrict__ X, float* __restrict__ G,
                                           int i0s, int r0, int rows, int c0,
                                           float* xs, int tid) {
    const int JW = W / 32;                    // 6 (W=192) or 2 (W=64)
    int ia = tid >> 5;
    int jb = tid & 31;
    float acc[4][JW];
#pragma unroll
    for (int a = 0; a < 4; ++a)
#pragma unroll
        for (int u = 0; u < JW; ++u) acc[a][u] = 0.f;
    for (int rb = 0; rb < rows; rb += 16) {
        __syncthreads();
        for (int lin = tid; lin < 4 * W; lin += 256) {
            int r = lin / (W / 4), f4 = lin % (W / 4);
            *(float4*)&xs[r * W + f4 * 4] =
                *(const float4*)&X[(size_t)(r0 + rb + r) * KD + c0 + f4 * 4];
        }
        __syncthreads();
#pragma unroll 4
        for (int r = 0; r < 16; ++r) {
            float4 xi = *(const float4*)&xs[r * W + i0s + ia * 4];
            float xj[JW];
#pragma unroll
            for (int u = 0; u < JW; ++u) xj[u] = xs[r * W + jb * JW + u];
#pragma unroll
            for (int a = 0; a < 4; ++a)
#pragma unroll
                for (int u = 0; u < JW; ++u)
                    acc[a][u] = fmaf(xi[a], xj[u], acc[a][u]);
        }
    }
#pragma unroll
    for (int a = 0; a < 4; ++a) {
        int i = i0s + ia * 4 + a;
#pragma unroll
        for (int u = 0; u < JW; ++u)
            atomicAdd(&G[i * W + jb * JW + u], acc[a][u]);
    }
}

// ---------------- fused Gram (HEAD) + GEMM (R10) ----------------
__global__ __launch_bounds__(256, 4)
void gemm_gram_kernel(const short* __restrict__ Zs, const short* __restrict__ Es,
                      const float* __restrict__ z2s, const float* __restrict__ e2s,
                      u64* __restrict__ packed, float* __restrict__ scal,
                      float* __restrict__ part_m, float* __restrict__ part_z,
                      float* __restrict__ part_w,
                      float* __restrict__ candD, int* __restrict__ candN,
                      int* __restrict__ ncand,
                      const float* __restrict__ znorm, const float* __restrict__ enorm,
                      float* __restrict__ Gbuf,
                      const float* __restrict__ SVeS, const float* __restrict__ SVeV,
                      const float* __restrict__ SVzS, const float* __restrict__ SVzV,
                      const float* __restrict__ mompart,
                      float* __restrict__ SV, float* __restrict__ mom) {
    __shared__ __align__(16) char smem[32768];
    const int gid = blockIdx.x, tid = threadIdx.x;

    if (gid < NGRAM) {                        // =============== GRAM path ===============
        int b = gid;
        float* xs = (float*)smem;
        float* r1 = (float*)(smem + 12288);
        float* r2 = (float*)(smem + 13312);

        if (b == 140) {                       // SV reduce
            int c = tid;
            float s = 0.f, v = 0.f;
            for (int j = 0; j < NZB; ++j) { s += SVzS[(size_t)j * 256 + c]; v += SVzV[(size_t)j * 256 + c]; }
            SV[c] = s; SV[256 + c] = v;
            s = 0.f; v = 0.f;
            for (int j = 0; j < NCB; ++j) { s += SVeS[(size_t)j * 256 + c]; v += SVeV[(size_t)j * 256 + c]; }
            SV[512 + c] = s; SV[768 + c] = v;
            return;
        }
        if (b == 141) {                       // moments reduce
            int q = tid & 3, grp = tid >> 2;
            float accE = 0.f, accZ = 0.f;
            for (int j = grp; j < NCB; j += 64) accE += mompart[j * 4 + q];
            for (int j = NCB + grp; j < NCB + NZB; j += 64) accZ += mompart[j * 4 + q];
            r1[tid] = accE; r2[tid] = accZ;
            __syncthreads();
            for (int st = 32; st > 0; st >>= 1) {
                if (grp < st) { r1[tid] += r1[tid + st * 4]; r2[tid] += r2[tid + st * 4]; }
                __syncthreads();
            }
            if (grp == 0) { mom[4 + q] = r1[q]; mom[q] = r2[q]; }
            return;
        }
        // strips: [0,96) E-g | [96,112) E-k | [112,136) Z-g | [136,140) Z-k
        if (b < 96) {
            gram_strip<192>(enorm, Gbuf + 4096, (b >> 4) * 32, (b & 15) * 1024, 1024, 64, xs, tid);
        } else if (b < 112) {
            int l = b - 96;
            gram_strip<64>(enorm, Gbuf, (l >> 3) * 32, (l & 7) * 2048, 2048, 0, xs, tid);
        } else if (b < 136) {
            int l = b - 112;
            gram_strip<192>(znorm, Gbuf + 45056, (l >> 2) * 32, (l & 3) * 1024, 1024, 64, xs, tid);
        } else {
            int l = b - 136;
            gram_strip<64>(znorm, Gbuf + 40960, (l >> 1) * 32, (l & 1) * 2048, 2048, 0, xs, tid);
        }
        return;
    }

    // =============== GEMM path ===============
    short* As = (short*)smem;                 // [128][64]
    short* Bs = As + 128 * 64;
    const int g = gid - NGRAM;
    const int lane = tid & 63, wid = tid >> 6;
    const int wm = wid >> 1, wn = wid & 1;
    const int t0 = (g & 31) * 128, n0 = (g >> 5) * 128;

    f32x4 acc[4][4];
#pragma unroll
    for (int bi = 0; bi < 4; ++bi)
#pragma unroll
        for (int bj = 0; bj < 4; ++bj) {
            f32x4 zz = {0.f, 0.f, 0.f, 0.f};
            acc[bi][bj] = zz;
        }

    auto stage = [&](int k0) {
        const int rb0 = wid * 32;
#pragma unroll
        for (int c2 = 0; c2 < 4; ++c2) {
            int rb = rb0 + c2 * 8;
            int row = rb + (lane >> 3);
            int q = (lane & 7) ^ (lane >> 3);   // XOR-quad swizzle (rb%8==0)
            async_load16(Zs + (size_t)(t0 + row) * K3 + k0 + q * 8, &As[rb * 64]);
            async_load16(Es + (size_t)(n0 + row) * K3 + k0 + q * 8, &Bs[rb * 64]);
        }
    };
    auto compute_half = [&](int s) {
        bf16x8 bfv[4];
#pragma unroll
        for (int bj = 0; bj < 4; ++bj) {
            int brow = wn * 64 + bj * 16 + (lane & 15);
            int q = ((s << 2) | (lane >> 4)) ^ (brow & 7);
            bfv[bj] = *reinterpret_cast<const bf16x8*>(&Bs[brow * 64 + q * 8]);
        }
#pragma unroll
        for (int bi = 0; bi < 4; ++bi) {
            int arow = wm * 64 + bi * 16 + (lane & 15);
            int q = ((s << 2) | (lane >> 4)) ^ (arow & 7);
            bf16x8 af = *reinterpret_cast<const bf16x8*>(&As[arow * 64 + q * 8]);
#pragma unroll
            for (int bj = 0; bj < 4; ++bj)
                acc[bi][bj] = __builtin_amdgcn_mfma_f32_16x16x32_bf16(
                    af, bfv[bj], acc[bi][bj], 0, 0, 0);
        }
    };

    int k0 = 0;
    for (int r = 0; r < 12; ++r) {
        stage(k0); __syncthreads();
        compute_half(0); compute_half(1);
        __syncthreads(); k0 += 64;
    }

    // ---- epilogue ----
    u64*   tokmin = (u64*)smem;               // [128][2]
    float* bmf    = (float*)(smem + 2048);    // [128]
    float* bthr   = (float*)(smem + 2560);    // [128]
    float* pzw    = (float*)(smem + 3072);    // [128][2][2]

    float e2sv[4];
#pragma unroll
    for (int bj = 0; bj < 4; ++bj)
        e2sv[bj] = e2s[n0 + wn * 64 + bj * 16 + (lane & 15)];

#pragma unroll
    for (int bi = 0; bi < 4; ++bi) {
        u64 pmin[4] = {~0ull, ~0ull, ~0ull, ~0ull};
        f32x4 z4 = *reinterpret_cast<const f32x4*>(
            &z2s[t0 + wm * 64 + bi * 16 + (lane >> 4) * 4]);
#pragma unroll
        for (int reg = 0; reg < 4; ++reg) {
#pragma unroll
            for (int bj = 0; bj < 4; ++bj) {
                float d = z4[reg] + e2sv[bj] + acc[bi][bj][reg];
                int n = n0 + wn * 64 + bj * 16 + (lane & 15);
                u64 pv = (((u64)__float_as_uint(d)) << 32) | (unsigned)n;
                if (pv < pmin[reg]) pmin[reg] = pv;
            }
        }
#pragma unroll
        for (int m = 1; m < 16; m <<= 1)
#pragma unroll
            for (int reg = 0; reg < 4; ++reg) {
                u64 o = __shfl_xor(pmin[reg], m, 64);
                if (o < pmin[reg]) pmin[reg] = o;
            }
        if ((lane & 15) == 0) {
#pragma unroll
            for (int reg = 0; reg < 4; ++reg) {
                int tl = wm * 64 + bi * 16 + (lane >> 4) * 4 + reg;
                tokmin[tl * 2 + wn] = pmin[reg];
            }
        }
    }
    __syncthreads();

    if (tid < 128) {
        int tl = tid;
        u64 bm = tokmin[tl * 2], b1 = tokmin[tl * 2 + 1];
        if (b1 < bm) bm = b1;
        u64 old = atomicMin(&packed[t0 + tl], bm);
        u64 gb = (old < bm) ? old : bm;
        float d_bmin = __uint_as_float((unsigned)(bm >> 32));
        bmf[tl] = -100.f * d_bmin;
        bthr[tl] = __uint_as_float((unsigned)(gb >> 32)) + DCUT;
    }
    __syncthreads();

#pragma unroll
    for (int bi = 0; bi < 4; ++bi) {
        float ez[4] = {0.f, 0.f, 0.f, 0.f}, ew[4] = {0.f, 0.f, 0.f, 0.f};
        f32x4 z4 = *reinterpret_cast<const f32x4*>(
            &z2s[t0 + wm * 64 + bi * 16 + (lane >> 4) * 4]);
#pragma unroll
        for (int reg = 0; reg < 4; ++reg) {
            int tl = wm * 64 + bi * 16 + (lane >> 4) * 4 + reg;
            int t = t0 + tl;
            float m_b = bmf[tl], thr = bthr[tl];
#pragma unroll
            for (int bj = 0; bj < 4; ++bj) {
                float d = z4[reg] + e2sv[bj] + acc[bi][bj][reg];
                float a = -100.f * d;
                float e = __expf(a - m_b);
                ez[reg] += e;
                ew[reg] = fmaf(a, e, ew[reg]);
                if (d <= thr) {
                    int pos = atomicAdd(&ncand[t], 1);
                    if (pos < CAP) {
                        candD[(size_t)t * CAP + pos] = d;
                        candN[(size_t)t * CAP + pos] = n0 + wn * 64 + bj * 16 + (lane & 15);
                    }
                }
            }
        }
#pragma unroll
        for (int m = 1; m < 16; m <<= 1)
#pragma unroll
            for (int reg = 0; reg < 4; ++reg) {
                ez[reg] += __shfl_xor(ez[reg], m, 64);
                ew[reg] += __shfl_xor(ew[reg], m, 64);
            }
        if ((lane & 15) == 0) {
#pragma unroll
            for (int reg = 0; reg < 4; ++reg) {
                int tl = wm * 64 + bi * 16 + (lane >> 4) * 4 + reg;
                pzw[(tl * 2 + wn) * 2 + 0] = ez[reg];
                pzw[(tl * 2 + wn) * 2 + 1] = ew[reg];
            }
        }
    }
    __syncthreads();

    if (tid < 128) {
        int tl = tid;
        size_t o = (size_t)(g >> 5) * T_TOK + t0 + tl;
        part_m[o] = bmf[tl];
        part_z[o] = pzw[tl * 4 + 0] + pzw[tl * 4 + 2];
        part_w[o] = pzw[tl * 4 + 1] + pzw[tl * 4 + 3];
    }
}

// ---------------- combine + zq + scatter + last-block finalize ----------------
__global__ __launch_bounds__(256)
void combine_final_kernel(const float* __restrict__ part_m, const float* __restrict__ part_z,
                          const float* __restrict__ part_w, const u64* __restrict__ packed,
                          const float* __restrict__ enorm, const float* __restrict__ znorm,
                          const float* __restrict__ candD, const int* __restrict__ candN,
                          const int* __restrict__ ncand, float* __restrict__ avg_num,
                          float* __restrict__ scal, int* __restrict__ done_ctr,
                          const float* __restrict__ G, const float* __restrict__ SV,
                          const float* __restrict__ mom, float* __restrict__ out) {
    __shared__ float sm[32][8], sz[32][8], sw[32][8];
    __shared__ float Ms[32], Zts[32];
    __shared__ int idxs[32];
    __shared__ float q_lds[256][33];
    __shared__ float red[256];
    __shared__ int lastf;
    int tid = threadIdx.x, tl = tid & 31, q = tid >> 5;
    int tbase = blockIdx.x * 32;
    int t = tbase + tl;

    // phase 1: online-softmax combine (8-way split over 128 n-blocks)
    float m = -3.0e38f, Z = 0.f, W = 0.f;
    for (int nb = q * 16; nb < q * 16 + 16; ++nb) {
        size_t o = (size_t)nb * T_TOK + t;
        float mb = part_m[o], zb = part_z[o], wb = part_w[o];
        if (mb > m) { float s = __expf(m - mb); Z *= s; W *= s; m = mb; }
        float s2 = __expf(mb - m);
        Z = fmaf(zb, s2, Z); W = fmaf(wb, s2, W);
    }
    sm[tl][q] = m; sz[tl][q] = Z; sw[tl][q] = W;
    __syncthreads();
    if (tid < 32) {
        float M = sm[tid][0], Zt = sz[tid][0], Wt = sw[tid][0];
#pragma unroll
        for (int qq = 1; qq < 8; ++qq) {
            float mb = sm[tid][qq], Zb = sz[tid][qq], Wb = sw[tid][qq];
            if (mb > M) { float s = __expf(M - mb); Zt *= s; Wt *= s; M = mb; }
            float s2 = __expf(mb - M);
            Zt = fmaf(Zb, s2, Zt); Wt = fmaf(Wb, s2, Wt);
        }
        int tt = tbase + tid;
        Ms[tid] = M; Zts[tid] = Zt;
        u64 pv = packed[tt];
        int idx = (int)(pv & 0xFFFFFFFFull);
        idxs[tid] = idx;
        out[1048581 + tt] = (float)idx;
        float ent = M + logf(Zt) - Wt / Zt;
#pragma unroll
        for (int mm = 1; mm < 32; mm <<= 1) ent += __shfl_xor(ent, mm, 64);
        if (tid == 0) atomicAdd(&scal[3], ent);
    }
    __syncthreads();

    // phase 2: z_q gather + transpose + vq loss (32 tokens)
    float sdq = 0.f;
    for (int tl2 = 0; tl2 < 32; ++tl2) {
        int tt = tbase + tl2;
        float qv = enorm[(size_t)idxs[tl2] * KD + tid];
        q_lds[tid][tl2] = qv;
        float zc = znorm[(size_t)tt * KD + tid];
        float df = qv - zc;
        sdq = fmaf(df, df, sdq);
    }
    __syncthreads();
    {
        int bb = tbase >> 10, hw0 = tbase & 1023;
        int cg = tid >> 5, hwl = tid & 31;
        for (int c0 = 0; c0 < 256; c0 += 8) {
            int c = c0 + cg;
            out[(((size_t)(bb * 256 + c)) << 10) + hw0 + hwl] = q_lds[c][hwl];
        }
    }
    red[tid] = sdq;
    __syncthreads();
    for (int s = 128; s > 0; s >>= 1) { if (tid < s) red[tid] += red[tid + s]; __syncthreads(); }
    if (tid == 0) atomicAdd(&scal[2], red[0]);

    // phase 3: avg_probs scatter (8 lanes per token)
    {
        int tok = tid >> 3, sub = tid & 7;
        int tt = tbase + tok;
        int nc = min(ncand[tt], CAP);
        float M = Ms[tok], Zt = Zts[tok];
        for (int i = sub; i < nc; i += 8) {
            float a = -100.f * candD[(size_t)tt * CAP + i];
            atomicAdd(&avg_num[candN[(size_t)tt * CAP + i]], __expf(a - M) / Zt);
        }
    }

    // phase 4: last block does finalize
    __syncthreads();
    __threadfence();
    if (tid == 0) lastf = (atomicAdd(done_ctr, 1) == 127) ? 1 : 0;
    __syncthreads();
    if (!lastf) return;
    __threadfence();

    float s = 0.f;
    for (int n = tid; n < NE; n += 256) {
        float avg = atomicAdd(&avg_num[n], 0.f) * (1.f / 4096.f);
        s += avg * logf(avg + 1e-5f);
    }
    red[tid] = s; __syncthreads();
    for (int st = 128; st > 0; st >>= 1) { if (tid < st) red[tid] += red[tid + st]; __syncthreads(); }
    float avg_ent_neg = red[0];
    __syncthreads();

    const float* G_ek = G;
    const float* G_eg = G + 4096;
    const float* G_zk = G + 40960;
    const float* G_zg = G + 45056;
    float rk = 0.f, rg = 0.f;
    for (int i = tid; i < 4096; i += 256)  rk = fmaf(G_zk[i], G_ek[i], rk);
    for (int i = tid; i < 36864; i += 256) rg = fmaf(G_zg[i], G_eg[i], rg);
    {
        int c = tid;
        float v = SV[256 + c] * SV[512 + c] + SV[c] * SV[768 + c];
        if (c < 64) rk -= v; else rg -= v;
    }
    red[tid] = 4.f * rk; __syncthreads();
    for (int st = 128; st > 0; st >>= 1) { if (tid < st) red[tid] += red[tid + st]; __syncthreads(); }
    float red_k = red[0];
    __syncthreads();
    red[tid] = 4.f * rg; __syncthreads();
    for (int st = 128; st > 0; st >>= 1) { if (tid < st) red[tid] += red[tid + st]; __syncthreads(); }
    float red_g = red[0];

    if (tid == 0) {
        float term1k = NE * mom[1] + 2.f * mom[0] * mom[4] + T_TOK * mom[5];
        float term1g = NE * mom[3] + 2.f * mom[2] * mom[6] + T_TOK * mom[7];
        float sdk2 = term1k + red_k;
        float sdg2 = term1g + red_g;
        float avg_ent = -avg_ent_neg;
        float se = atomicAdd(&scal[3], 0.f) * (1.f / 4096.f);
        float vq = atomicAdd(&scal[2], 0.f) * (1.f / 1048576.f);
        out[1048576] = vq;
        out[1048577] = 0.25f * vq;
        out[1048578] = 0.1f * (se - avg_ent);
        out[1048579] = sdk2 * (1.f / 4096.f);
        out[1048580] = sdg2 * (1.f / 4096.f);
    }
}

// ---------------- host ----------------
extern "C" void kernel_launch(void* const* d_in, const int* in_sizes, int n_in,
                              void* d_out, int out_size, void* d_ws, size_t ws_size,
                              hipStream_t stream) {
    const float* z  = (const float*)d_in[0];
    const float* wk = (const float*)d_in[1];
    const float* wg = (const float*)d_in[2];
    float* out = (float*)d_out;

    char* ws = (char*)d_ws;
    size_t off = 0;
    auto alloc = [&](size_t bytes) {
        void* p = ws + off;
        off += (bytes + 255) & ~(size_t)255;
        return p;
    };
    float* enorm  = (float*)alloc((size_t)NE * KD * 4);
    float* znorm  = (float*)alloc((size_t)T_TOK * KD * 4);
    short* Es     = (short*)alloc((size_t)NE * K3 * 2);
    short* Zs     = (short*)alloc((size_t)T_TOK * K3 * 2);
    float* e2k    = (float*)alloc(NE * 4);
    float* e2s    = (float*)alloc(NE * 4);
    float* z2k    = (float*)alloc(T_TOK * 4);
    float* z2s    = (float*)alloc(T_TOK * 4);
    u64*   packed = (u64*)alloc(T_TOK * 8);
    int*   ncand  = (int*)alloc(T_TOK * 4);
    float* part_m = (float*)alloc((size_t)(NE / 128) * T_TOK * 4);
    float* part_z = (float*)alloc((size_t)(NE / 128) * T_TOK * 4);
    float* part_w = (float*)alloc((size_t)(NE / 128) * T_TOK * 4);
    float* candD  = (float*)alloc((size_t)T_TOK * CAP * 4);
    int*   candN  = (int*)alloc((size_t)T_TOK * CAP * 4);
    float* avg_num= (float*)alloc(NE * 4);
    float* scal   = (float*)alloc(8 * 4);
    float* Gbuf   = (float*)alloc(81920 * 4);
    float* SV     = (float*)alloc(1024 * 4);
    float* momv   = (float*)alloc(8 * 4);
    float* SVeS   = (float*)alloc((size_t)NCB * 256 * 4);
    float* SVeV   = (float*)alloc((size_t)NCB * 256 * 4);
    float* SVzS   = (float*)alloc((size_t)NZB * 256 * 4);
    float* SVzV   = (float*)alloc((size_t)NZB * 256 * 4);
    float* mompart= (float*)alloc((size_t)(NCB + NZB) * 4 * 4);
    int*   done_ctr = (int*)alloc(256);

    megaprep_kernel<<<NCB + NZB + 8, 256, 0, stream>>>(
        wk, wg, z, enorm, e2k, e2s, Es, znorm, z2k, z2s, Zs,
        SVeS, SVeV, SVzS, SVzV, mompart, packed, avg_num, ncand, scal, Gbuf, done_ctr);

    gemm_gram_kernel<<<NGRAM + NGEMM, 256, 0, stream>>>(
        Zs, Es, z2s, e2s, packed, scal, part_m, part_z, part_w,
        candD, candN, ncand, znorm, enorm, Gbuf,
        SVeS, SVeV, SVzS, SVzV, mompart, SV, momv);

    combine_final_kernel<<<T_TOK / 32, 256, 0, stream>>>(
        part_m, part_z, part_w, packed, enorm, znorm,
        candD, candN, ncand, avg_num, scal, done_ctr, Gbuf, SV, momv, out);
}

// Round 13
// 359.001 us; speedup vs baseline: 1.0900x; 1.0394x over previous
//
#include <hip/hip_runtime.h>

// VectorQuantizer forward, MI355X. Split-bf16 MFMA GEMM (hi/lo, 3 products,
// K extended 256->768). Epilogue: argmin + per-block online-softmax partials
// (exact entropy) + racy-shrinking-threshold candidate capture. d^2-norm split
// in closed form (Gram + colsums + moments). R13: megaprep reverted to exact
// R10 (R12's chunk-write cost ~10us of conversion VALU); combine_final split
// 128->256 blocks (16 tokens each) for 2x parallelism. Gemm = R10 bit-exact.
// 3 kernels. T=4096 tokens, NE=16384 codes.

#define T_TOK 4096
#define NE    16384
#define KD    256
#define K3    768          // 3x split-extended K
#define CAP   768          // candidate slots per token (avg_probs only)
#define DCUT  0.15f        // capture window above best-so-far global min

#define NCB   512          // code prep blocks (32 rows each)
#define NZB   128          // z prep blocks (32 tokens each)
#define NGRAM 142          // gram strip jobs + 2 reduce blocks (placed first)
#define NGEMM 4096         // gemm blocks (32 x 128)

typedef __attribute__((ext_vector_type(8))) short bf16x8;
typedef __attribute__((ext_vector_type(4))) float f32x4;
typedef unsigned long long u64;

__device__ __forceinline__ short f2bf(float f) {
    unsigned u = __float_as_uint(f);
    u = (u + 0x7FFFu + ((u >> 16) & 1u)) >> 16;   // round-to-nearest-even
    return (short)u;
}
__device__ __forceinline__ float bf2f(short s) {
    return __uint_as_float(((unsigned)(unsigned short)s) << 16);
}

__device__ __forceinline__ void async_load16(const void* g, void* l) {
    __builtin_amdgcn_global_load_lds(
        (const __attribute__((address_space(1))) void*)g,
        (__attribute__((address_space(3))) void*)l, 16, 0, 0);
}

// ---------------- megaprep: codes | z | init, branch on blockIdx (R10 exact) ---------
__global__ __launch_bounds__(256)
void megaprep_kernel(const float* __restrict__ wk, const float* __restrict__ wg,
                     const float* __restrict__ z,
                     float* __restrict__ enorm, float* __restrict__ e2k,
                     float* __restrict__ e2s, short* __restrict__ Es,
                     float* __restrict__ znorm, float* __restrict__ z2k,
                     float* __restrict__ z2s, short* __restrict__ Zs,
                     float* __restrict__ SVeS, float* __restrict__ SVeV,
                     float* __restrict__ SVzS, float* __restrict__ SVzV,
                     float* __restrict__ mompart,
                     u64* __restrict__ packed, float* __restrict__ avg_num,
                     int* __restrict__ ncand, float* __restrict__ scal,
                     float* __restrict__ G, int* __restrict__ done_ctr) {
    int b = blockIdx.x, tid = threadIdx.x;
    if (b >= NCB + NZB) {                    // ---- init branch ----
        int gid = (b - NCB - NZB) * 256 + tid;
        for (int i = gid; i < 81920; i += 2048) G[i] = 0.f;
        for (int i = gid; i < NE; i += 2048) avg_num[i] = 0.f;
        for (int i = gid; i < T_TOK; i += 2048) { packed[i] = ~0ull; ncand[i] = 0; }
        if (gid < 8) scal[gid] = 0.f;
        if (gid == 8) *done_ctr = 0;
        return;
    }

    __shared__ float xs[32][257];            // 32.9 KB
    __shared__ float ps[32][8];
    __shared__ float rnorm[32][2];
    __shared__ float rw[32][2];

    if (b < NCB) {                           // ---- codes branch ----
        int n0 = b * 32;
#pragma unroll
        for (int i = 0; i < 8; ++i) {
            int idx = tid + i * 256;
            xs[idx >> 6][idx & 63] = wk[(size_t)n0 * 64 + idx];
        }
#pragma unroll
        for (int i = 0; i < 24; ++i) {
            int idx = tid + i * 256;
            xs[idx / 192][64 + idx % 192] = wg[(size_t)n0 * 192 + idx];
        }
        __syncthreads();
        {
            int r = tid & 31, part = tid >> 5;
            float s = 0.f;
            for (int j = 0; j < 32; ++j) { float v = xs[r][part * 32 + j]; s = fmaf(v, v, s); }
            ps[r][part] = s;
        }
        __syncthreads();
        if (tid < 32) {
            float sk = ps[tid][0] + ps[tid][1];
            float sg = ps[tid][2] + ps[tid][3] + ps[tid][4] + ps[tid][5] + ps[tid][6] + ps[tid][7];
            float nk = fmaxf(sqrtf(sk), 1e-12f), ng = fmaxf(sqrtf(sg), 1e-12f);
            float ek2 = sk / (nk * nk), eg2 = sg / (ng * ng);
            rnorm[tid][0] = 1.f / nk; rnorm[tid][1] = 1.f / ng;
            rw[tid][0] = ek2; rw[tid][1] = eg2;
            e2k[n0 + tid] = ek2; e2s[n0 + tid] = ek2 + eg2;
        }
        __syncthreads();
        int c = tid;
        for (int i = 0; i < 32; ++i) {
            float y = xs[i][c] * rnorm[i][(c < 64) ? 0 : 1];
            enorm[(size_t)(n0 + i) * KD + c] = y;
            short h = f2bf(y);          float hf = bf2f(h);
            short l = f2bf(y - hf);
            short sh = f2bf(-2.f * hf), sl = f2bf(-2.f * bf2f(l));
            short* Er = Es + (size_t)(n0 + i) * K3;
            if (c < 64) { Er[c] = sh; Er[64 + c] = sl; Er[128 + c] = sh; }
            else { int cc = c - 64; Er[192 + cc] = sh; Er[384 + cc] = sl; Er[576 + cc] = sh; }
        }
        {
            int sel = (c < 64) ? 0 : 1;
            float S = 0.f, V = 0.f;
            for (int r = 0; r < 32; ++r) {
                float y = xs[r][c] * rnorm[r][sel];
                S += y; V = fmaf(rw[r][sel], y, V);
            }
            SVeS[(size_t)b * 256 + c] = S;
            SVeV[(size_t)b * 256 + c] = V;
        }
        if (tid < 32) {
            float a = rw[tid][0], g = rw[tid][1];
            float s0 = a, s1 = a * a, s2 = g, s3 = g * g;
#pragma unroll
            for (int m = 1; m < 32; m <<= 1) {
                s0 += __shfl_xor(s0, m, 64); s1 += __shfl_xor(s1, m, 64);
                s2 += __shfl_xor(s2, m, 64); s3 += __shfl_xor(s3, m, 64);
            }
            if (tid == 0) {
                mompart[b * 4 + 0] = s0; mompart[b * 4 + 1] = s1;
                mompart[b * 4 + 2] = s2; mompart[b * 4 + 3] = s3;
            }
        }
    } else {                                 // ---- z branch ----
        int jz = b - NCB;
        int t0 = jz * 32;
        int bb = t0 >> 10, hw0 = t0 & 1023;
#pragma unroll
        for (int i = 0; i < 32; ++i) {
            int idx = tid + i * 256;
            int cc = idx >> 5, hwl = idx & 31;
            xs[hwl][cc] = z[(((size_t)bb * 256 + cc) << 10) + hw0 + hwl];
        }
        __syncthreads();
        {
            int r = tid & 31, part = tid >> 5;
            float s = 0.f;
            for (int j = 0; j < 32; ++j) { float v = xs[r][part * 32 + j]; s = fmaf(v, v, s); }
            ps[r][part] = s;
        }
        __syncthreads();
        if (tid < 32) {
            float sk = ps[tid][0] + ps[tid][1];
            float sg = ps[tid][2] + ps[tid][3] + ps[tid][4] + ps[tid][5] + ps[tid][6] + ps[tid][7];
            float nk = fmaxf(sqrtf(sk), 1e-12f), ng = fmaxf(sqrtf(sg), 1e-12f);
            float zk2 = sk / (nk * nk), zg2 = sg / (ng * ng);
            rnorm[tid][0] = 1.f / nk; rnorm[tid][1] = 1.f / ng;
            rw[tid][0] = zk2; rw[tid][1] = zg2;
            z2k[t0 + tid] = zk2; z2s[t0 + tid] = zk2 + zg2;
        }
        __syncthreads();
        int c = tid;
        for (int i = 0; i < 32; ++i) {
            float y = xs[i][c] * rnorm[i][(c < 64) ? 0 : 1];
            znorm[(size_t)(t0 + i) * KD + c] = y;
            short h = f2bf(y);      float hf = bf2f(h);
            short l = f2bf(y - hf);
            short* Zr = Zs + (size_t)(t0 + i) * K3;
            if (c < 64) { Zr[c] = h; Zr[64 + c] = h; Zr[128 + c] = l; }
            else { int cc = c - 64; Zr[192 + cc] = h; Zr[384 + cc] = h; Zr[576 + cc] = l; }
        }
        {
            int sel = (c < 64) ? 0 : 1;
            float S = 0.f, V = 0.f;
            for (int r = 0; r < 32; ++r) {
                float y = xs[r][c] * rnorm[r][sel];
                S += y; V = fmaf(rw[r][sel], y, V);
            }
            SVzS[(size_t)jz * 256 + c] = S;
            SVzV[(size_t)jz * 256 + c] = V;
        }
        if (tid < 32) {
            float a = rw[tid][0], g = rw[tid][1];
            float s0 = a, s1 = a * a, s2 = g, s3 = g * g;
#pragma unroll
            for (int m = 1; m < 32; m <<= 1) {
                s0 += __shfl_xor(s0, m, 64); s1 += __shfl_xor(s1, m, 64);
                s2 += __shfl_xor(s2, m, 64); s3 += __shfl_xor(s3, m, 64);
            }
            if (tid == 0) {
                mompart[b * 4 + 0] = s0; mompart[b * 4 + 1] = s1;
                mompart[b * 4 + 2] = s2; mompart[b * 4 + 3] = s3;
            }
        }
    }
}

// ---------------- gram strip job: 32-col i-strip x full W, register acc (R10) --------
template <int W>
__device__ __forceinline__ void gram_strip(const float* __restrict__ X, float* __restrict__ G,
                                           int i0s, int r0, int rows, int c0,
                                           float* xs, int tid) {
    const int JW = W / 32;                    // 6 (W=192) or 2 (W=64)
    int ia = tid >> 5;
    int jb = tid & 31;
    float acc[4][JW];
#pragma unroll
    for (int a = 0; a < 4; ++a)
#pragma unroll
        for (int u = 0; u < JW; ++u) acc[a][u] = 0.f;
    for (int rb = 0; rb < rows; rb += 16) {
        __syncthreads();
        for (int lin = tid; lin < 4 * W; lin += 256) {
            int r = lin / (W / 4), f4 = lin % (W / 4);
            *(float4*)&xs[r * W + f4 * 4] =
                *(const float4*)&X[(size_t)(r0 + rb + r) * KD + c0 + f4 * 4];
        }
        __syncthreads();
#pragma unroll 4
        for (int r = 0; r < 16; ++r) {
            float4 xi = *(const float4*)&xs[r * W + i0s + ia * 4];
            float xj[JW];
#pragma unroll
            for (int u = 0; u < JW; ++u) xj[u] = xs[r * W + jb * JW + u];
#pragma unroll
            for (int a = 0; a < 4; ++a)
#pragma unroll
                for (int u = 0; u < JW; ++u)
                    acc[a][u] = fmaf(xi[a], xj[u], acc[a][u]);
        }
    }
#pragma unroll
    for (int a = 0; a < 4; ++a) {
        int i = i0s + ia * 4 + a;
#pragma unroll
        for (int u = 0; u < JW; ++u)
            atomicAdd(&G[i * W + jb * JW + u], acc[a][u]);
    }
}

// ---------------- fused Gram (HEAD) + GEMM (R10 exact) ----------------
__global__ __launch_bounds__(256, 4)
void gemm_gram_kernel(const short* __restrict__ Zs, const short* __restrict__ Es,
                      const float* __restrict__ z2s, const float* __restrict__ e2s,
                      u64* __restrict__ packed, float* __restrict__ scal,
                      float* __restrict__ part_m, float* __restrict__ part_z,
                      float* __restrict__ part_w,
                      float* __restrict__ candD, int* __restrict__ candN,
                      int* __restrict__ ncand,
                      const float* __restrict__ znorm, const float* __restrict__ enorm,
                      float* __restrict__ Gbuf,
                      const float* __restrict__ SVeS, const float* __restrict__ SVeV,
                      const float* __restrict__ SVzS, const float* __restrict__ SVzV,
                      const float* __restrict__ mompart,
                      float* __restrict__ SV, float* __restrict__ mom) {
    __shared__ __align__(16) char smem[32768];
    const int gid = blockIdx.x, tid = threadIdx.x;

    if (gid < NGRAM) {                        // =============== GRAM path ===============
        int b = gid;
        float* xs = (float*)smem;
        float* r1 = (float*)(smem + 12288);
        float* r2 = (float*)(smem + 13312);

        if (b == 140) {                       // SV reduce
            int c = tid;
            float s = 0.f, v = 0.f;
            for (int j = 0; j < NZB; ++j) { s += SVzS[(size_t)j * 256 + c]; v += SVzV[(size_t)j * 256 + c]; }
            SV[c] = s; SV[256 + c] = v;
            s = 0.f; v = 0.f;
            for (int j = 0; j < NCB; ++j) { s += SVeS[(size_t)j * 256 + c]; v += SVeV[(size_t)j * 256 + c]; }
            SV[512 + c] = s; SV[768 + c] = v;
            return;
        }
        if (b == 141) {                       // moments reduce
            int q = tid & 3, grp = tid >> 2;
            float accE = 0.f, accZ = 0.f;
            for (int j = grp; j < NCB; j += 64) accE += mompart[j * 4 + q];
            for (int j = NCB + grp; j < NCB + NZB; j += 64) accZ += mompart[j * 4 + q];
            r1[tid] = accE; r2[tid] = accZ;
            __syncthreads();
            for (int st = 32; st > 0; st >>= 1) {
                if (grp < st) { r1[tid] += r1[tid + st * 4]; r2[tid] += r2[tid + st * 4]; }
                __syncthreads();
            }
            if (grp == 0) { mom[4 + q] = r1[q]; mom[q] = r2[q]; }
            return;
        }
        // strips: [0,96) E-g | [96,112) E-k | [112,136) Z-g | [136,140) Z-k
        if (b < 96) {
            gram_strip<192>(enorm, Gbuf + 4096, (b >> 4) * 32, (b & 15) * 1024, 1024, 64, xs, tid);
        } else if (b < 112) {
            int l = b - 96;
            gram_strip<64>(enorm, Gbuf, (l >> 3) * 32, (l & 7) * 2048, 2048, 0, xs, tid);
        } else if (b < 136) {
            int l = b - 112;
            gram_strip<192>(znorm, Gbuf + 45056, (l >> 2) * 32, (l & 3) * 1024, 1024, 64, xs, tid);
        } else {
            int l = b - 136;
            gram_strip<64>(znorm, Gbuf + 40960, (l >> 1) * 32, (l & 1) * 2048, 2048, 0, xs, tid);
        }
        return;
    }

    // =============== GEMM path ===============
    short* As = (short*)smem;                 // [128][64]
    short* Bs = As + 128 * 64;
    const int g = gid - NGRAM;
    const int lane = tid & 63, wid = tid >> 6;
    const int wm = wid >> 1, wn = wid & 1;
    const int t0 = (g & 31) * 128, n0 = (g >> 5) * 128;

    f32x4 acc[4][4];
#pragma unroll
    for (int bi = 0; bi < 4; ++bi)
#pragma unroll
        for (int bj = 0; bj < 4; ++bj) {
            f32x4 zz = {0.f, 0.f, 0.f, 0.f};
            acc[bi][bj] = zz;
        }

    auto stage = [&](int k0) {
        const int rb0 = wid * 32;
#pragma unroll
        for (int c2 = 0; c2 < 4; ++c2) {
            int rb = rb0 + c2 * 8;
            int row = rb + (lane >> 3);
            int q = (lane & 7) ^ (lane >> 3);   // XOR-quad swizzle (rb%8==0)
            async_load16(Zs + (size_t)(t0 + row) * K3 + k0 + q * 8, &As[rb * 64]);
            async_load16(Es + (size_t)(n0 + row) * K3 + k0 + q * 8, &Bs[rb * 64]);
        }
    };
    auto compute_half = [&](int s) {
        bf16x8 bfv[4];
#pragma unroll
        for (int bj = 0; bj < 4; ++bj) {
            int brow = wn * 64 + bj * 16 + (lane & 15);
            int q = ((s << 2) | (lane >> 4)) ^ (brow & 7);
            bfv[bj] = *reinterpret_cast<const bf16x8*>(&Bs[brow * 64 + q * 8]);
        }
#pragma unroll
        for (int bi = 0; bi < 4; ++bi) {
            int arow = wm * 64 + bi * 16 + (lane & 15);
            int q = ((s << 2) | (lane >> 4)) ^ (arow & 7);
            bf16x8 af = *reinterpret_cast<const bf16x8*>(&As[arow * 64 + q * 8]);
#pragma unroll
            for (int bj = 0; bj < 4; ++bj)
                acc[bi][bj] = __builtin_amdgcn_mfma_f32_16x16x32_bf16(
                    af, bfv[bj], acc[bi][bj], 0, 0, 0);
        }
    };

    int k0 = 0;
    for (int r = 0; r < 12; ++r) {
        stage(k0); __syncthreads();
        compute_half(0); compute_half(1);
        __syncthreads(); k0 += 64;
    }

    // ---- epilogue ----
    u64*   tokmin = (u64*)smem;               // [128][2]
    float* bmf    = (float*)(smem + 2048);    // [128]
    float* bthr   = (float*)(smem + 2560);    // [128]
    float* pzw    = (float*)(smem + 3072);    // [128][2][2]

    float e2sv[4];
#pragma unroll
    for (int bj = 0; bj < 4; ++bj)
        e2sv[bj] = e2s[n0 + wn * 64 + bj * 16 + (lane & 15)];

#pragma unroll
    for (int bi = 0; bi < 4; ++bi) {
        u64 pmin[4] = {~0ull, ~0ull, ~0ull, ~0ull};
        f32x4 z4 = *reinterpret_cast<const f32x4*>(
            &z2s[t0 + wm * 64 + bi * 16 + (lane >> 4) * 4]);
#pragma unroll
        for (int reg = 0; reg < 4; ++reg) {
#pragma unroll
            for (int bj = 0; bj < 4; ++bj) {
                float d = z4[reg] + e2sv[bj] + acc[bi][bj][reg];
                int n = n0 + wn * 64 + bj * 16 + (lane & 15);
                u64 pv = (((u64)__float_as_uint(d)) << 32) | (unsigned)n;
                if (pv < pmin[reg]) pmin[reg] = pv;
            }
        }
#pragma unroll
        for (int m = 1; m < 16; m <<= 1)
#pragma unroll
            for (int reg = 0; reg < 4; ++reg) {
                u64 o = __shfl_xor(pmin[reg], m, 64);
                if (o < pmin[reg]) pmin[reg] = o;
            }
        if ((lane & 15) == 0) {
#pragma unroll
            for (int reg = 0; reg < 4; ++reg) {
                int tl = wm * 64 + bi * 16 + (lane >> 4) * 4 + reg;
                tokmin[tl * 2 + wn] = pmin[reg];
            }
        }
    }
    __syncthreads();

    if (tid < 128) {
        int tl = tid;
        u64 bm = tokmin[tl * 2], b1 = tokmin[tl * 2 + 1];
        if (b1 < bm) bm = b1;
        u64 old = atomicMin(&packed[t0 + tl], bm);
        u64 gb = (old < bm) ? old : bm;
        float d_bmin = __uint_as_float((unsigned)(bm >> 32));
        bmf[tl] = -100.f * d_bmin;
        bthr[tl] = __uint_as_float((unsigned)(gb >> 32)) + DCUT;
    }
    __syncthreads();

#pragma unroll
    for (int bi = 0; bi < 4; ++bi) {
        float ez[4] = {0.f, 0.f, 0.f, 0.f}, ew[4] = {0.f, 0.f, 0.f, 0.f};
        f32x4 z4 = *reinterpret_cast<const f32x4*>(
            &z2s[t0 + wm * 64 + bi * 16 + (lane >> 4) * 4]);
#pragma unroll
        for (int reg = 0; reg < 4; ++reg) {
            int tl = wm * 64 + bi * 16 + (lane >> 4) * 4 + reg;
            int t = t0 + tl;
            float m_b = bmf[tl], thr = bthr[tl];
#pragma unroll
            for (int bj = 0; bj < 4; ++bj) {
                float d = z4[reg] + e2sv[bj] + acc[bi][bj][reg];
                float a = -100.f * d;
                float e = __expf(a - m_b);
                ez[reg] += e;
                ew[reg] = fmaf(a, e, ew[reg]);
                if (d <= thr) {
                    int pos = atomicAdd(&ncand[t], 1);
                    if (pos < CAP) {
                        candD[(size_t)t * CAP + pos] = d;
                        candN[(size_t)t * CAP + pos] = n0 + wn * 64 + bj * 16 + (lane & 15);
                    }
                }
            }
        }
#pragma unroll
        for (int m = 1; m < 16; m <<= 1)
#pragma unroll
            for (int reg = 0; reg < 4; ++reg) {
                ez[reg] += __shfl_xor(ez[reg], m, 64);
                ew[reg] += __shfl_xor(ew[reg], m, 64);
            }
        if ((lane & 15) == 0) {
#pragma unroll
            for (int reg = 0; reg < 4; ++reg) {
                int tl = wm * 64 + bi * 16 + (lane >> 4) * 4 + reg;
                pzw[(tl * 2 + wn) * 2 + 0] = ez[reg];
                pzw[(tl * 2 + wn) * 2 + 1] = ew[reg];
            }
        }
    }
    __syncthreads();

    if (tid < 128) {
        int tl = tid;
        size_t o = (size_t)(g >> 5) * T_TOK + t0 + tl;
        part_m[o] = bmf[tl];
        part_z[o] = pzw[tl * 4 + 0] + pzw[tl * 4 + 2];
        part_w[o] = pzw[tl * 4 + 1] + pzw[tl * 4 + 3];
    }
}

// ---------------- combine + zq + scatter + last-block finalize ----------------
// 256 blocks x 16 tokens (R13: was 128 x 32 -> half-idle GPU).
__global__ __launch_bounds__(256)
void combine_final_kernel(const float* __restrict__ part_m, const float* __restrict__ part_z,
                          const float* __restrict__ part_w, const u64* __restrict__ packed,
                          const float* __restrict__ enorm, const float* __restrict__ znorm,
                          const float* __restrict__ candD, const int* __restrict__ candN,
                          const int* __restrict__ ncand, float* __restrict__ avg_num,
                          float* __restrict__ scal, int* __restrict__ done_ctr,
                          const float* __restrict__ G, const float* __restrict__ SV,
                          const float* __restrict__ mom, float* __restrict__ out) {
    __shared__ float sm[16][16], sz[16][16], sw[16][16];
    __shared__ float Ms[16], Zts[16];
    __shared__ int idxs[16];
    __shared__ float q_lds[256][17];
    __shared__ float red[256];
    __shared__ int lastf;
    int tid = threadIdx.x, tl = tid & 15, q = tid >> 4;   // 16 groups x 8 n-blocks
    int tbase = blockIdx.x * 16;
    int t = tbase + tl;

    // phase 1: online-softmax combine (16-way split over 128 n-blocks)
    float m = -3.0e38f, Z = 0.f, W = 0.f;
    for (int nb = q * 8; nb < q * 8 + 8; ++nb) {
        size_t o = (size_t)nb * T_TOK + t;
        float mb = part_m[o], zb = part_z[o], wb = part_w[o];
        if (mb > m) { float s = __expf(m - mb); Z *= s; W *= s; m = mb; }
        float s2 = __expf(mb - m);
        Z = fmaf(zb, s2, Z); W = fmaf(wb, s2, W);
    }
    sm[tl][q] = m; sz[tl][q] = Z; sw[tl][q] = W;
    __syncthreads();
    if (tid < 16) {
        float M = sm[tid][0], Zt = sz[tid][0], Wt = sw[tid][0];
#pragma unroll
        for (int qq = 1; qq < 16; ++qq) {
            float mb = sm[tid][qq], Zb = sz[tid][qq], Wb = sw[tid][qq];
            if (mb > M) { float s = __expf(M - mb); Zt *= s; Wt *= s; M = mb; }
            float s2 = __expf(mb - M);
            Zt = fmaf(Zb, s2, Zt); Wt = fmaf(Wb, s2, Wt);
        }
        int tt = tbase + tid;
        Ms[tid] = M; Zts[tid] = Zt;
        u64 pv = packed[tt];
        int idx = (int)(pv & 0xFFFFFFFFull);
        idxs[tid] = idx;
        out[1048581 + tt] = (float)idx;
        float ent = M + logf(Zt) - Wt / Zt;
#pragma unroll
        for (int mm = 1; mm < 16; mm <<= 1) ent += __shfl_xor(ent, mm, 64);
        if (tid == 0) atomicAdd(&scal[3], ent);
    }
    __syncthreads();

    // phase 2: z_q gather + transpose + vq loss (16 tokens)
    float sdq = 0.f;
    for (int tl2 = 0; tl2 < 16; ++tl2) {
        int tt = tbase + tl2;
        float qv = enorm[(size_t)idxs[tl2] * KD + tid];
        q_lds[tid][tl2] = qv;
        float zc = znorm[(size_t)tt * KD + tid];
        float df = qv - zc;
        sdq = fmaf(df, df, sdq);
    }
    __syncthreads();
    {
        int bb = tbase >> 10, hw0 = tbase & 1023;
        int cg = tid >> 4, hwl = tid & 15;
        for (int c0 = 0; c0 < 256; c0 += 16) {
            int c = c0 + cg;
            out[(((size_t)(bb * 256 + c)) << 10) + hw0 + hwl] = q_lds[c][hwl];
        }
    }
    red[tid] = sdq;
    __syncthreads();
    for (int s = 128; s > 0; s >>= 1) { if (tid < s) red[tid] += red[tid + s]; __syncthreads(); }
    if (tid == 0) atomicAdd(&scal[2], red[0]);

    // phase 3: avg_probs scatter (16 lanes per token)
    {
        int tok = tid >> 4, sub = tid & 15;
        int tt = tbase + tok;
        int nc = min(ncand[tt], CAP);
        float M = Ms[tok], Zt = Zts[tok];
        for (int i = sub; i < nc; i += 16) {
            float a = -100.f * candD[(size_t)tt * CAP + i];
            atomicAdd(&avg_num[candN[(size_t)tt * CAP + i]], __expf(a - M) / Zt);
        }
    }

    // phase 4: last block does finalize
    __syncthreads();
    __threadfence();
    if (tid == 0) lastf = (atomicAdd(done_ctr, 1) == 255) ? 1 : 0;
    __syncthreads();
    if (!lastf) return;
    __threadfence();

    float s = 0.f;
    for (int n = tid; n < NE; n += 256) {
        float avg = atomicAdd(&avg_num[n], 0.f) * (1.f / 4096.f);
        s += avg * logf(avg + 1e-5f);
    }
    red[tid] = s; __syncthreads();
    for (int st = 128; st > 0; st >>= 1) { if (tid < st) red[tid] += red[tid + st]; __syncthreads(); }
    float avg_ent_neg = red[0];
    __syncthreads();

    const float* G_ek = G;
    const float* G_eg = G + 4096;
    const float* G_zk = G + 40960;
    const float* G_zg = G + 45056;
    float rk = 0.f, rg = 0.f;
    for (int i = tid; i < 4096; i += 256)  rk = fmaf(G_zk[i], G_ek[i], rk);
    for (int i = tid; i < 36864; i += 256) rg = fmaf(G_zg[i], G_eg[i], rg);
    {
        int c = tid;
        float v = SV[256 + c] * SV[512 + c] + SV[c] * SV[768 + c];
        if (c < 64) rk -= v; else rg -= v;
    }
    red[tid] = 4.f * rk; __syncthreads();
    for (int st = 128; st > 0; st >>= 1) { if (tid < st) red[tid] += red[tid + st]; __syncthreads(); }
    float red_k = red[0];
    __syncthreads();
    red[tid] = 4.f * rg; __syncthreads();
    for (int st = 128; st > 0; st >>= 1) { if (tid < st) red[tid] += red[tid + st]; __syncthreads(); }
    float red_g = red[0];

    if (tid == 0) {
        float term1k = NE * mom[1] + 2.f * mom[0] * mom[4] + T_TOK * mom[5];
        float term1g = NE * mom[3] + 2.f * mom[2] * mom[6] + T_TOK * mom[7];
        float sdk2 = term1k + red_k;
        float sdg2 = term1g + red_g;
        float avg_ent = -avg_ent_neg;
        float se = atomicAdd(&scal[3], 0.f) * (1.f / 4096.f);
        float vq = atomicAdd(&scal[2], 0.f) * (1.f / 1048576.f);
        out[1048576] = vq;
        out[1048577] = 0.25f * vq;
        out[1048578] = 0.1f * (se - avg_ent);
        out[1048579] = sdk2 * (1.f / 4096.f);
        out[1048580] = sdg2 * (1.f / 4096.f);
    }
}

// ---------------- host ----------------
extern "C" void kernel_launch(void* const* d_in, const int* in_sizes, int n_in,
                              void* d_out, int out_size, void* d_ws, size_t ws_size,
                              hipStream_t stream) {
    const float* z  = (const float*)d_in[0];
    const float* wk = (const float*)d_in[1];
    const float* wg = (const float*)d_in[2];
    float* out = (float*)d_out;

    char* ws = (char*)d_ws;
    size_t off = 0;
    auto alloc = [&](size_t bytes) {
        void* p = ws + off;
        off += (bytes + 255) & ~(size_t)255;
        return p;
    };
    float* enorm  = (float*)alloc((size_t)NE * KD * 4);
    float* znorm  = (float*)alloc((size_t)T_TOK * KD * 4);
    short* Es     = (short*)alloc((size_t)NE * K3 * 2);
    short* Zs     = (short*)alloc((size_t)T_TOK * K3 * 2);
    float* e2k    = (float*)alloc(NE * 4);
    float* e2s    = (float*)alloc(NE * 4);
    float* z2k    = (float*)alloc(T_TOK * 4);
    float* z2s    = (float*)alloc(T_TOK * 4);
    u64*   packed = (u64*)alloc(T_TOK * 8);
    int*   ncand  = (int*)alloc(T_TOK * 4);
    float* part_m = (float*)alloc((size_t)(NE / 128) * T_TOK * 4);
    float* part_z = (float*)alloc((size_t)(NE / 128) * T_TOK * 4);
    float* part_w = (float*)alloc((size_t)(NE / 128) * T_TOK * 4);
    float* candD  = (float*)alloc((size_t)T_TOK * CAP * 4);
    int*   candN  = (int*)alloc((size_t)T_TOK * CAP * 4);
    float* avg_num= (float*)alloc(NE * 4);
    float* scal   = (float*)alloc(8 * 4);
    float* Gbuf   = (float*)alloc(81920 * 4);
    float* SV     = (float*)alloc(1024 * 4);
    float* momv   = (float*)alloc(8 * 4);
    float* SVeS   = (float*)alloc((size_t)NCB * 256 * 4);
    float* SVeV   = (float*)alloc((size_t)NCB * 256 * 4);
    float* SVzS   = (float*)alloc((size_t)NZB * 256 * 4);
    float* SVzV   = (float*)alloc((size_t)NZB * 256 * 4);
    float* mompart= (float*)alloc((size_t)(NCB + NZB) * 4 * 4);
    int*   done_ctr = (int*)alloc(256);

    megaprep_kernel<<<NCB + NZB + 8, 256, 0, stream>>>(
        wk, wg, z, enorm, e2k, e2s, Es, znorm, z2k, z2s, Zs,
        SVeS, SVeV, SVzS, SVzV, mompart, packed, avg_num, ncand, scal, Gbuf, done_ctr);

    gemm_gram_kernel<<<NGRAM + NGEMM, 256, 0, stream>>>(
        Zs, Es, z2s, e2s, packed, scal, part_m, part_z, part_w,
        candD, candN, ncand, znorm, enorm, Gbuf,
        SVeS, SVeV, SVzS, SVzV, mompart, SV, momv);

    combine_final_kernel<<<256, 256, 0, stream>>>(
        part_m, part_z, part_w, packed, enorm, znorm,
        candD, candN, ncand, avg_num, scal, done_ctr, Gbuf, SV, momv, out);
}